// Round 8
// baseline (153.584 us; speedup 1.0000x reference)
//
#include <hip/hip_runtime.h>
#include <math.h>

// CapsNet dynamic routing, all-MFMA (16x16x32 only), hi/lo split packed into K.
//   x: [512,1152,8] f32, w: [10,1152,16,8] f32, out: [512,10,16] f32
// p0:  w -> bf16 hi/lo, natural [c][n][d][k] and transposed [c][n][k][d] (merged, once).
// p1:  s0 partials via mfma(K = 4n x 8k), 3-term hi/lo split, VGPR accum. NS1=36.
// p2:  per n-pair: logits via mfma(A=[wT_hi|wT_lo] K=2*d, B=[o0h|o0h]) + 4 FMA + 1 shfl;
//      softmax in-lane; s1 via per-n mfma(A=[w_hi|w_lo|w_hi|*], B=[x_hi|x_hi|x_lo|0]),
//      scaled after by c1 (1 shfl/c). NS2=48. Contiguous per-wave n + unroll-2 for ILP.
// Partials -> P[ns][b][160]; reduce_squash sums + squashes.

#define BB   512
#define NN1  1152
#define CD   160
#define XB   (NN1*8)           // 9216
#define WELEM (10*NN1*16*8)    // 1474560

typedef __attribute__((ext_vector_type(8))) short bf16x8;
typedef __attribute__((ext_vector_type(4))) float f32x4;

#define MFMA32(a, b, c) __builtin_amdgcn_mfma_f32_16x16x32_bf16(a, b, c, 0, 0, 0)
#define ZERO4 ((f32x4){0.f, 0.f, 0.f, 0.f})

__device__ __forceinline__ short f2bf(float f) {
    unsigned u = __builtin_bit_cast(unsigned, f);
    u += 0x7FFFu + ((u >> 16) & 1u);
    return (short)(u >> 16);
}
__device__ __forceinline__ float bf2f(short s) {
    unsigned u = ((unsigned)(unsigned short)s) << 16;
    return __builtin_bit_cast(float, u);
}
__device__ __forceinline__ bf16x8 cvt_hi8(f32x4 a, f32x4 b) {
    bf16x8 r;
#pragma unroll
    for (int i = 0; i < 4; ++i) { r[i] = f2bf(a[i]); r[4 + i] = f2bf(b[i]); }
    return r;
}
__device__ __forceinline__ void cvt_hilo8(f32x4 a, f32x4 b, bf16x8& h, bf16x8& l) {
#pragma unroll
    for (int i = 0; i < 4; ++i) {
        short t = f2bf(a[i]); h[i] = t; l[i] = f2bf(a[i] - bf2f(t));
        t = f2bf(b[i]); h[4 + i] = t; l[4 + i] = f2bf(b[i] - bf2f(t));
    }
}

// ---------------- p0: w -> {wnat, wT} hi/lo in one pass ----------------
__global__ void p0(const float* __restrict__ w,
                   short* __restrict__ wnh, short* __restrict__ wnl,
                   short* __restrict__ wth, short* __restrict__ wtl)
{
    int i = blockIdx.x * 256 + threadIdx.x;      // 5760*256 == WELEM
    int k = i & 7, d = (i >> 3) & 15, row = i >> 7;   // row = c*1152+n
    float f = w[i];
    short h = f2bf(f);
    short l = f2bf(f - bf2f(h));
    wnh[i] = h;
    wnl[i] = l;
    int ti = row * 128 + k * 16 + d;
    wth[ti] = h;
    wtl[ti] = l;
}

// ---------------- p1: s0 partials, mfma over (4n x 8k) ----------------
template<int NS>
__global__ __launch_bounds__(256, 4) void caps_p1(
    const float* __restrict__ x, const short* __restrict__ wnh, const short* __restrict__ wnl,
    float* __restrict__ P)
{
    constexpr int NT = NN1 / NS;
    constexpr int QPW = NT / 16;     // quads per wave
    static_assert(NT % 16 == 0, "balanced quads");
    __shared__ float red[2][2560];

    const int ns = blockIdx.x, bt = blockIdx.y;
    const int tid = threadIdx.x, lane = tid & 63, wv = tid >> 6;
    const int lo = lane & 15, g = lane >> 4;
    const int btile = bt * 16;

    f32x4 acc[10];
#pragma unroll
    for (int c = 0; c < 10; ++c) acc[c] = ZERO4;

#pragma unroll 2
    for (int it = 0; it < QPW; ++it) {
        const int n0 = ns * NT + (wv * QPW + it) * 4;
        const float* px = x + (size_t)(btile + lo) * XB + (size_t)(n0 + g) * 8;
        f32x4 x0 = *(const f32x4*)px;
        f32x4 x1 = *(const f32x4*)(px + 4);
        bf16x8 ah, al;
        cvt_hilo8(x0, x1, ah, al);
#pragma unroll
        for (int c = 0; c < 10; ++c) {
            size_t off = (((size_t)c * NN1 + n0 + g) * 16 + lo) * 8;
            bf16x8 bh = *(const bf16x8*)(wnh + off);
            bf16x8 bl = *(const bf16x8*)(wnl + off);
            acc[c] = MFMA32(ah, bh, acc[c]);
            acc[c] = MFMA32(al, bh, acc[c]);
            acc[c] = MFMA32(ah, bl, acc[c]);
        }
    }

    // 4-wave reduce; C layout: col=lo=d, row=g*4+e=b-local
    if (wv == 1 || wv == 3) {
        float* s = red[wv >> 1];
#pragma unroll
        for (int c = 0; c < 10; ++c)
#pragma unroll
            for (int e = 0; e < 4; ++e) s[c * 256 + (g * 4 + e) * 16 + lo] = acc[c][e];
    }
    __syncthreads();
    if (wv == 0) {
#pragma unroll
        for (int c = 0; c < 10; ++c)
#pragma unroll
            for (int e = 0; e < 4; ++e) acc[c][e] += red[0][c * 256 + (g * 4 + e) * 16 + lo];
    } else if (wv == 2) {
#pragma unroll
        for (int c = 0; c < 10; ++c)
#pragma unroll
            for (int e = 0; e < 4; ++e) {
                int idx = c * 256 + (g * 4 + e) * 16 + lo;
                red[1][idx] += acc[c][e];
            }
    }
    __syncthreads();
    if (wv == 0) {
        float* dst = P + (size_t)ns * BB * CD;
#pragma unroll
        for (int c = 0; c < 10; ++c)
#pragma unroll
            for (int e = 0; e < 4; ++e)
                dst[(size_t)(btile + g * 4 + e) * CD + c * 16 + lo] =
                    acc[c][e] + red[1][c * 256 + (g * 4 + e) * 16 + lo];
    }
}

// ------- reduce over ns + squash(alpha*S) -------
__global__ void reduce_squash(const float* __restrict__ P, float* __restrict__ out,
                              int nsplit, float asq)
{
    int t = blockIdx.x * 256 + threadIdx.x;      // 320*256 == 81920
    float s = 0.f;
    const float* p = P + t;
    for (int ns = 0; ns < nsplit; ++ns, p += (size_t)BB * CD) s += *p;
    float sq = s * s;
#pragma unroll
    for (int m = 1; m < 16; m <<= 1) sq += __shfl_xor(sq, m, 64);
    float qq = asq * sq;
    float sc = qq / (1.f + qq) / sqrtf(sq);
    out[t] = s * sc;
}

// ---------------- p2: R-GEMM logits + in-lane softmax + scaled s1-GEMM ----------------
template<int NS>
__global__ __launch_bounds__(256, 3) void caps_p2(
    const float* __restrict__ x,
    const short* __restrict__ wnh, const short* __restrict__ wnl,
    const short* __restrict__ wth, const short* __restrict__ wtl,
    const float* __restrict__ o0, float* __restrict__ P)
{
    constexpr int NT = NN1 / NS;
    constexpr int PPW = NT / 8;      // n-pairs per wave
    static_assert(NT % 8 == 0, "balanced pairs");
    __shared__ float red[2][2560];

    const int ns = blockIdx.x, bt = blockIdx.y;
    const int tid = threadIdx.x, lane = tid & 63, wv = tid >> 6;
    const int lo = lane & 15, g = lane >> 4;
    const int btile = bt * 16;
    const int b = btile + lo;
    const int ghalf = g & 1, gtop = g >> 1;
    const int n2r = lo >> 3, kr = lo & 7;

    const short* tsel = (g < 2) ? wth : wtl;     // R-GEMM A: hi for g<2, lo for g>=2
    const short* wsel = ghalf ? wnl : wnh;       // s1 A: hi,lo,hi,(junk: B zeroes blk3)

    // R-GEMM B: o0_hi[b, (g&1)*8 + 0..7] per c
    bf16x8 o0B[10];
    {
        const float* po = o0 + (size_t)b * CD + ghalf * 8;
#pragma unroll
        for (int c = 0; c < 10; ++c)
            o0B[c] = cvt_hi8(*(const f32x4*)(po + c * 16), *(const f32x4*)(po + c * 16 + 4));
    }

    f32x4 acc[10];
#pragma unroll
    for (int c = 0; c < 10; ++c) acc[c] = ZERO4;

    const bf16x8 z8 = {0, 0, 0, 0, 0, 0, 0, 0};

#pragma unroll 2
    for (int it = 0; it < PPW; ++it) {
        const int n0 = ns * NT + (wv * PPW + it) * 2;
        const float* px = x + (size_t)b * XB + (size_t)n0 * 8;
        f32x4 x0a = *(const f32x4*)px,       x0b = *(const f32x4*)(px + 4);
        f32x4 x1a = *(const f32x4*)(px + 8), x1b = *(const f32x4*)(px + 12);

        bf16x8 xh0, xl0, xh1, xl1;
        cvt_hilo8(x0a, x0b, xh0, xl0);
        cvt_hilo8(x1a, x1b, xh1, xl1);

        // s1 B-fragments: [x_hi | x_hi | x_lo | 0] along K
        bf16x8 Bx0, Bx1;
        if (g == 3)      { Bx0 = z8;  Bx1 = z8;  }
        else if (g == 2) { Bx0 = xl0; Bx1 = xl1; }
        else             { Bx0 = xh0; Bx1 = xh1; }

        // x slice for logit dot: x[b, n0+gtop, (g&1)*4 + e]
        f32x4 xq = x0a;
        if (!gtop &&  ghalf) xq = x0b;
        if ( gtop && !ghalf) xq = x1a;
        if ( gtop &&  ghalf) xq = x1b;

        // ---- pass 1: logits ----
        float L[10];
#pragma unroll
        for (int c = 0; c < 10; ++c) {
            const short* atp = tsel + (((size_t)c * NN1 + n0 + n2r) * 8 + kr) * 16 + ghalf * 8;
            bf16x8 At = *(const bf16x8*)atp;
            f32x4 r = MFMA32(At, o0B[c], ZERO4);
            float lp = r[0] * xq[0] + r[1] * xq[1] + r[2] * xq[2] + r[3] * xq[3];
            L[c] = lp + __shfl_xor(lp, 16, 64);
        }
        // ---- softmax in-lane (lane owns (b, n0+gtop)) ----
        float mx = L[0];
#pragma unroll
        for (int c = 1; c < 10; ++c) mx = fmaxf(mx, L[c]);
        float den = 0.f;
#pragma unroll
        for (int c = 0; c < 10; ++c) { L[c] = __expf(L[c] - mx); den += L[c]; }
        float inv = 1.f / den;

        // ---- pass 2: s1 += c1 * (w . x) per n ----
#pragma unroll
        for (int c = 0; c < 10; ++c) {
            float c1own = L[c] * inv;
            float c1oth = __shfl_xor(c1own, 32, 64);
            float c1n0 = gtop ? c1oth : c1own;
            float c1n1 = gtop ? c1own : c1oth;
            const short* ap = wsel + (((size_t)c * NN1 + n0) * 16 + lo) * 8;
            bf16x8 A0 = *(const bf16x8*)ap;
            bf16x8 A1 = *(const bf16x8*)(ap + 128);
            f32x4 y0 = MFMA32(A0, Bx0, ZERO4);
            f32x4 y1 = MFMA32(A1, Bx1, ZERO4);
#pragma unroll
            for (int e = 0; e < 4; ++e) acc[c][e] += c1n0 * y0[e] + c1n1 * y1[e];
        }
    }

    // 4-wave reduce; C layout: col=lo=b-local, row=g*4+e=d
    if (wv == 1 || wv == 3) {
        float* s = red[wv >> 1];
#pragma unroll
        for (int c = 0; c < 10; ++c)
#pragma unroll
            for (int e = 0; e < 4; ++e) s[c * 256 + (g * 4 + e) * 16 + lo] = acc[c][e];
    }
    __syncthreads();
    if (wv == 0) {
#pragma unroll
        for (int c = 0; c < 10; ++c)
#pragma unroll
            for (int e = 0; e < 4; ++e) acc[c][e] += red[0][c * 256 + (g * 4 + e) * 16 + lo];
    } else if (wv == 2) {
#pragma unroll
        for (int c = 0; c < 10; ++c)
#pragma unroll
            for (int e = 0; e < 4; ++e) {
                int idx = c * 256 + (g * 4 + e) * 16 + lo;
                red[1][idx] += acc[c][e];
            }
    }
    __syncthreads();
    if (wv == 0) {
        float* dst = P + (size_t)ns * BB * CD;
#pragma unroll
        for (int c = 0; c < 10; ++c)
#pragma unroll
            for (int e = 0; e < 4; ++e)
                dst[(size_t)(btile + lo) * CD + c * 16 + g * 4 + e] =
                    acc[c][e] + red[1][c * 256 + (g * 4 + e) * 16 + lo];
    }
}

extern "C" void kernel_launch(void* const* d_in, const int* in_sizes, int n_in,
                              void* d_out, int out_size, void* d_ws, size_t ws_size,
                              hipStream_t stream)
{
    (void)in_sizes; (void)n_in; (void)out_size;
    const float* x = (const float*)d_in[0];
    const float* w = (const float*)d_in[1];
    float* out = (float*)d_out;

    char* base = (char*)d_ws;
    short* wnh = (short*)(base);
    short* wnl = (short*)(base + 2949120);
    short* wth = (short*)(base + 5898240);
    short* wtl = (short*)(base + 8847360);
    float* o0  = (float*)(base + 11796480);
    float* P   = (float*)(base + 12124160);
    const size_t fixed = 12124160, slab = (size_t)BB * CD * sizeof(float);

    p0<<<WELEM / 256, 256, 0, stream>>>(w, wnh, wnl, wth, wtl);

#define LAUNCH_NS(NS1, NS2)                                                            \
    do {                                                                               \
        caps_p1<NS1><<<dim3(NS1, 32), 256, 0, stream>>>(x, wnh, wnl, P);               \
        reduce_squash<<<320, 256, 0, stream>>>(P, o0, NS1, 0.01f);                     \
        caps_p2<NS2><<<dim3(NS2, 32), 256, 0, stream>>>(x, wnh, wnl, wth, wtl, o0, P); \
        reduce_squash<<<320, 256, 0, stream>>>(P, out, NS2, 1.0f);                     \
    } while (0)

    if      (ws_size >= fixed + slab * 48) LAUNCH_NS(36, 48);   // p1: 2 quads/wave; p2: 3 pairs/wave
    else if (ws_size >= fixed + slab * 12) LAUNCH_NS(12, 12);
    else                                   LAUNCH_NS(4, 4);
#undef LAUNCH_NS
}

// Round 9
// 126.684 us; speedup vs baseline: 1.2123x; 1.2123x over previous
//
#include <hip/hip_runtime.h>
#include <math.h>

// CapsNet dynamic routing, all-MFMA (16x16x32 only), hi/lo split packed into K.
//   x: [512,1152,8] f32, w: [10,1152,16,8] f32, out: [512,10,16] f32
// p0:  w -> bf16 hi/lo, natural [c][n][d][k] and transposed [c][n][k][d] (merged, once).
// p1:  s0 partials via mfma(K = 4n x 8k), 3-term hi/lo split, VGPR accum. NS1=36, lb(256,4).
// p2:  per n-pair: logits via mfma(A=[wT_hi|wT_lo] K=2*d, B=[o0h|o0h]) + 4 FMA + 1 shfl;
//      softmax in-lane; s1 via per-n mfma, scaled by c1. NS2=48, lb(256,2) + unroll 2
//      (R8 lesson: unroll with lb(256,3)'s 84-VGPR cap spilled 360MB of scratch).
// Partials -> P[ns][b][160]; reduce_squash sums + squashes.

#define BB   512
#define NN1  1152
#define CD   160
#define XB   (NN1*8)           // 9216
#define WELEM (10*NN1*16*8)    // 1474560

typedef __attribute__((ext_vector_type(8))) short bf16x8;
typedef __attribute__((ext_vector_type(4))) float f32x4;

#define MFMA32(a, b, c) __builtin_amdgcn_mfma_f32_16x16x32_bf16(a, b, c, 0, 0, 0)
#define ZERO4 ((f32x4){0.f, 0.f, 0.f, 0.f})

__device__ __forceinline__ short f2bf(float f) {
    unsigned u = __builtin_bit_cast(unsigned, f);
    u += 0x7FFFu + ((u >> 16) & 1u);
    return (short)(u >> 16);
}
__device__ __forceinline__ float bf2f(short s) {
    unsigned u = ((unsigned)(unsigned short)s) << 16;
    return __builtin_bit_cast(float, u);
}
__device__ __forceinline__ bf16x8 cvt_hi8(f32x4 a, f32x4 b) {
    bf16x8 r;
#pragma unroll
    for (int i = 0; i < 4; ++i) { r[i] = f2bf(a[i]); r[4 + i] = f2bf(b[i]); }
    return r;
}
__device__ __forceinline__ void cvt_hilo8(f32x4 a, f32x4 b, bf16x8& h, bf16x8& l) {
#pragma unroll
    for (int i = 0; i < 4; ++i) {
        short t = f2bf(a[i]); h[i] = t; l[i] = f2bf(a[i] - bf2f(t));
        t = f2bf(b[i]); h[4 + i] = t; l[4 + i] = f2bf(b[i] - bf2f(t));
    }
}

// ---------------- p0: w -> {wnat, wT} hi/lo in one pass ----------------
__global__ void p0(const float* __restrict__ w,
                   short* __restrict__ wnh, short* __restrict__ wnl,
                   short* __restrict__ wth, short* __restrict__ wtl)
{
    int i = blockIdx.x * 256 + threadIdx.x;      // 5760*256 == WELEM
    int k = i & 7, d = (i >> 3) & 15, row = i >> 7;   // row = c*1152+n
    float f = w[i];
    short h = f2bf(f);
    short l = f2bf(f - bf2f(h));
    wnh[i] = h;
    wnl[i] = l;
    int ti = row * 128 + k * 16 + d;
    wth[ti] = h;
    wtl[ti] = l;
}

// ---------------- p1: s0 partials, mfma over (4n x 8k) ----------------
template<int NS>
__global__ __launch_bounds__(256, 4) void caps_p1(
    const float* __restrict__ x, const short* __restrict__ wnh, const short* __restrict__ wnl,
    float* __restrict__ P)
{
    constexpr int NT = NN1 / NS;
    constexpr int QPW = NT / 16;     // quads per wave
    static_assert(NT % 16 == 0, "balanced quads");
    __shared__ float red[2][2560];

    const int ns = blockIdx.x, bt = blockIdx.y;
    const int tid = threadIdx.x, lane = tid & 63, wv = tid >> 6;
    const int lo = lane & 15, g = lane >> 4;
    const int btile = bt * 16;

    f32x4 acc[10];
#pragma unroll
    for (int c = 0; c < 10; ++c) acc[c] = ZERO4;

#pragma unroll 2
    for (int it = 0; it < QPW; ++it) {
        const int n0 = ns * NT + (wv * QPW + it) * 4;
        const float* px = x + (size_t)(btile + lo) * XB + (size_t)(n0 + g) * 8;
        f32x4 x0 = *(const f32x4*)px;
        f32x4 x1 = *(const f32x4*)(px + 4);
        bf16x8 ah, al;
        cvt_hilo8(x0, x1, ah, al);
#pragma unroll
        for (int c = 0; c < 10; ++c) {
            size_t off = (((size_t)c * NN1 + n0 + g) * 16 + lo) * 8;
            bf16x8 bh = *(const bf16x8*)(wnh + off);
            bf16x8 bl = *(const bf16x8*)(wnl + off);
            acc[c] = MFMA32(ah, bh, acc[c]);
            acc[c] = MFMA32(al, bh, acc[c]);
            acc[c] = MFMA32(ah, bl, acc[c]);
        }
    }

    // 4-wave reduce; C layout: col=lo=d, row=g*4+e=b-local
    if (wv == 1 || wv == 3) {
        float* s = red[wv >> 1];
#pragma unroll
        for (int c = 0; c < 10; ++c)
#pragma unroll
            for (int e = 0; e < 4; ++e) s[c * 256 + (g * 4 + e) * 16 + lo] = acc[c][e];
    }
    __syncthreads();
    if (wv == 0) {
#pragma unroll
        for (int c = 0; c < 10; ++c)
#pragma unroll
            for (int e = 0; e < 4; ++e) acc[c][e] += red[0][c * 256 + (g * 4 + e) * 16 + lo];
    } else if (wv == 2) {
#pragma unroll
        for (int c = 0; c < 10; ++c)
#pragma unroll
            for (int e = 0; e < 4; ++e) {
                int idx = c * 256 + (g * 4 + e) * 16 + lo;
                red[1][idx] += acc[c][e];
            }
    }
    __syncthreads();
    if (wv == 0) {
        float* dst = P + (size_t)ns * BB * CD;
#pragma unroll
        for (int c = 0; c < 10; ++c)
#pragma unroll
            for (int e = 0; e < 4; ++e)
                dst[(size_t)(btile + g * 4 + e) * CD + c * 16 + lo] =
                    acc[c][e] + red[1][c * 256 + (g * 4 + e) * 16 + lo];
    }
}

// ------- reduce over ns + squash(alpha*S) -------
__global__ void reduce_squash(const float* __restrict__ P, float* __restrict__ out,
                              int nsplit, float asq)
{
    int t = blockIdx.x * 256 + threadIdx.x;      // 320*256 == 81920
    float s = 0.f;
    const float* p = P + t;
    for (int ns = 0; ns < nsplit; ++ns, p += (size_t)BB * CD) s += *p;
    float sq = s * s;
#pragma unroll
    for (int m = 1; m < 16; m <<= 1) sq += __shfl_xor(sq, m, 64);
    float qq = asq * sq;
    float sc = qq / (1.f + qq) / sqrtf(sq);
    out[t] = s * sc;
}

// ---------------- p2: R-GEMM logits + in-lane softmax + scaled s1-GEMM ----------------
template<int NS>
__global__ __launch_bounds__(256, 2) void caps_p2(
    const float* __restrict__ x,
    const short* __restrict__ wnh, const short* __restrict__ wnl,
    const short* __restrict__ wth, const short* __restrict__ wtl,
    const float* __restrict__ o0, float* __restrict__ P)
{
    constexpr int NT = NN1 / NS;
    constexpr int PPW = NT / 8;      // n-pairs per wave
    static_assert(NT % 8 == 0, "balanced pairs");
    __shared__ float red[2][2560];

    const int ns = blockIdx.x, bt = blockIdx.y;
    const int tid = threadIdx.x, lane = tid & 63, wv = tid >> 6;
    const int lo = lane & 15, g = lane >> 4;
    const int btile = bt * 16;
    const int b = btile + lo;
    const int ghalf = g & 1, gtop = g >> 1;
    const int n2r = lo >> 3, kr = lo & 7;

    const short* tsel = (g < 2) ? wth : wtl;     // R-GEMM A: hi for g<2, lo for g>=2
    const short* wsel = ghalf ? wnl : wnh;       // s1 A: hi,lo,hi,(junk: B zeroes blk3)

    // R-GEMM B: o0_hi[b, (g&1)*8 + 0..7] per c
    bf16x8 o0B[10];
    {
        const float* po = o0 + (size_t)b * CD + ghalf * 8;
#pragma unroll
        for (int c = 0; c < 10; ++c)
            o0B[c] = cvt_hi8(*(const f32x4*)(po + c * 16), *(const f32x4*)(po + c * 16 + 4));
    }

    f32x4 acc[10];
#pragma unroll
    for (int c = 0; c < 10; ++c) acc[c] = ZERO4;

    const bf16x8 z8 = {0, 0, 0, 0, 0, 0, 0, 0};

#pragma unroll 2
    for (int it = 0; it < PPW; ++it) {
        const int n0 = ns * NT + (wv * PPW + it) * 2;
        const float* px = x + (size_t)b * XB + (size_t)n0 * 8;
        f32x4 x0a = *(const f32x4*)px,       x0b = *(const f32x4*)(px + 4);
        f32x4 x1a = *(const f32x4*)(px + 8), x1b = *(const f32x4*)(px + 12);

        bf16x8 xh0, xl0, xh1, xl1;
        cvt_hilo8(x0a, x0b, xh0, xl0);
        cvt_hilo8(x1a, x1b, xh1, xl1);

        // s1 B-fragments: [x_hi | x_hi | x_lo | 0] along K
        bf16x8 Bx0, Bx1;
        if (g == 3)      { Bx0 = z8;  Bx1 = z8;  }
        else if (g == 2) { Bx0 = xl0; Bx1 = xl1; }
        else             { Bx0 = xh0; Bx1 = xh1; }

        // x slice for logit dot: x[b, n0+gtop, (g&1)*4 + e]
        f32x4 xq = x0a;
        if (!gtop &&  ghalf) xq = x0b;
        if ( gtop && !ghalf) xq = x1a;
        if ( gtop &&  ghalf) xq = x1b;

        // ---- pass 1: logits ----
        float L[10];
#pragma unroll
        for (int c = 0; c < 10; ++c) {
            const short* atp = tsel + (((size_t)c * NN1 + n0 + n2r) * 8 + kr) * 16 + ghalf * 8;
            bf16x8 At = *(const bf16x8*)atp;
            f32x4 r = MFMA32(At, o0B[c], ZERO4);
            float lp = r[0] * xq[0] + r[1] * xq[1] + r[2] * xq[2] + r[3] * xq[3];
            L[c] = lp + __shfl_xor(lp, 16, 64);
        }
        // ---- softmax in-lane (lane owns (b, n0+gtop)) ----
        float mx = L[0];
#pragma unroll
        for (int c = 1; c < 10; ++c) mx = fmaxf(mx, L[c]);
        float den = 0.f;
#pragma unroll
        for (int c = 0; c < 10; ++c) { L[c] = __expf(L[c] - mx); den += L[c]; }
        float inv = 1.f / den;

        // ---- pass 2: s1 += c1 * (w . x) per n ----
#pragma unroll
        for (int c = 0; c < 10; ++c) {
            float c1own = L[c] * inv;
            float c1oth = __shfl_xor(c1own, 32, 64);
            float c1n0 = gtop ? c1oth : c1own;
            float c1n1 = gtop ? c1own : c1oth;
            const short* ap = wsel + (((size_t)c * NN1 + n0) * 16 + lo) * 8;
            bf16x8 A0 = *(const bf16x8*)ap;
            bf16x8 A1 = *(const bf16x8*)(ap + 128);
            f32x4 y0 = MFMA32(A0, Bx0, ZERO4);
            f32x4 y1 = MFMA32(A1, Bx1, ZERO4);
#pragma unroll
            for (int e = 0; e < 4; ++e) acc[c][e] += c1n0 * y0[e] + c1n1 * y1[e];
        }
    }

    // 4-wave reduce; C layout: col=lo=b-local, row=g*4+e=d
    if (wv == 1 || wv == 3) {
        float* s = red[wv >> 1];
#pragma unroll
        for (int c = 0; c < 10; ++c)
#pragma unroll
            for (int e = 0; e < 4; ++e) s[c * 256 + (g * 4 + e) * 16 + lo] = acc[c][e];
    }
    __syncthreads();
    if (wv == 0) {
#pragma unroll
        for (int c = 0; c < 10; ++c)
#pragma unroll
            for (int e = 0; e < 4; ++e) acc[c][e] += red[0][c * 256 + (g * 4 + e) * 16 + lo];
    } else if (wv == 2) {
#pragma unroll
        for (int c = 0; c < 10; ++c)
#pragma unroll
            for (int e = 0; e < 4; ++e) {
                int idx = c * 256 + (g * 4 + e) * 16 + lo;
                red[1][idx] += acc[c][e];
            }
    }
    __syncthreads();
    if (wv == 0) {
        float* dst = P + (size_t)ns * BB * CD;
#pragma unroll
        for (int c = 0; c < 10; ++c)
#pragma unroll
            for (int e = 0; e < 4; ++e)
                dst[(size_t)(btile + lo) * CD + c * 16 + g * 4 + e] =
                    acc[c][e] + red[1][c * 256 + (g * 4 + e) * 16 + lo];
    }
}

extern "C" void kernel_launch(void* const* d_in, const int* in_sizes, int n_in,
                              void* d_out, int out_size, void* d_ws, size_t ws_size,
                              hipStream_t stream)
{
    (void)in_sizes; (void)n_in; (void)out_size;
    const float* x = (const float*)d_in[0];
    const float* w = (const float*)d_in[1];
    float* out = (float*)d_out;

    char* base = (char*)d_ws;
    short* wnh = (short*)(base);
    short* wnl = (short*)(base + 2949120);
    short* wth = (short*)(base + 5898240);
    short* wtl = (short*)(base + 8847360);
    float* o0  = (float*)(base + 11796480);
    float* P   = (float*)(base + 12124160);
    const size_t fixed = 12124160, slab = (size_t)BB * CD * sizeof(float);

    p0<<<WELEM / 256, 256, 0, stream>>>(w, wnh, wnl, wth, wtl);

#define LAUNCH_NS(NS1, NS2)                                                            \
    do {                                                                               \
        caps_p1<NS1><<<dim3(NS1, 32), 256, 0, stream>>>(x, wnh, wnl, P);               \
        reduce_squash<<<320, 256, 0, stream>>>(P, o0, NS1, 0.01f);                     \
        caps_p2<NS2><<<dim3(NS2, 32), 256, 0, stream>>>(x, wnh, wnl, wth, wtl, o0, P); \
        reduce_squash<<<320, 256, 0, stream>>>(P, out, NS2, 1.0f);                     \
    } while (0)

    if      (ws_size >= fixed + slab * 48) LAUNCH_NS(36, 48);   // p1: 2 quads/wave; p2: 3 pairs/wave
    else if (ws_size >= fixed + slab * 12) LAUNCH_NS(12, 12);
    else                                   LAUNCH_NS(4, 4);
#undef LAUNCH_NS
}

// Round 10
// 105.454 us; speedup vs baseline: 1.4564x; 1.2013x over previous
//
#include <hip/hip_runtime.h>
#include <math.h>

// CapsNet dynamic routing, all-MFMA (16x16x32 only), hi/lo split packed into K.
//   x: [512,1152,8] f32, w: [10,1152,16,8] f32, out: [512,10,16] f32
// p0:  w -> bf16 hi/lo natural [c][n][d][k] only (transposed arrays eliminated).
// p1:  s0 partials via mfma(K = 4n x 8k), 3-term hi/lo split, VGPR accum. NS1=36.
// p2:  per n-pair: pass1 mfma(A=[w_hi|w_lo|w_hi|*],B=[x_hi|x_hi|x_lo|0]) -> y = x_hat;
//      logits = in-lane dot(y, o0_f32) + shfl16 + shfl32 (both n's land in-lane);
//      softmax in-lane, c1 in-lane (no exchange); pass2 RELOADS A (opaque-laundered to
//      defeat CSE -> no 80-VGPR y residency), recomputes y, acc += c1*y.
//      Peak live ~115 VGPR -> no spill (R9's 62MB scratch was the killer).
// Partials -> P[ns][b][160]; reduce_squash sums + squashes.

#define BB   512
#define NN1  1152
#define CD   160
#define XB   (NN1*8)           // 9216
#define WELEM (10*NN1*16*8)    // 1474560

typedef __attribute__((ext_vector_type(8))) short bf16x8;
typedef __attribute__((ext_vector_type(4))) float f32x4;

#define MFMA32(a, b, c) __builtin_amdgcn_mfma_f32_16x16x32_bf16(a, b, c, 0, 0, 0)
#define ZERO4 ((f32x4){0.f, 0.f, 0.f, 0.f})

__device__ __forceinline__ short f2bf(float f) {
    unsigned u = __builtin_bit_cast(unsigned, f);
    u += 0x7FFFu + ((u >> 16) & 1u);
    return (short)(u >> 16);
}
__device__ __forceinline__ float bf2f(short s) {
    unsigned u = ((unsigned)(unsigned short)s) << 16;
    return __builtin_bit_cast(float, u);
}
__device__ __forceinline__ void cvt_hilo8(f32x4 a, f32x4 b, bf16x8& h, bf16x8& l) {
#pragma unroll
    for (int i = 0; i < 4; ++i) {
        short t = f2bf(a[i]); h[i] = t; l[i] = f2bf(a[i] - bf2f(t));
        t = f2bf(b[i]); h[4 + i] = t; l[4 + i] = f2bf(b[i] - bf2f(t));
    }
}
__device__ __forceinline__ int opaque_zero() {
    int z;
    asm volatile("v_mov_b32 %0, 0" : "=v"(z));
    return z;
}

// ---------------- p0: w -> wnat hi/lo ----------------
__global__ void p0(const float* __restrict__ w,
                   short* __restrict__ wnh, short* __restrict__ wnl)
{
    int i = blockIdx.x * 256 + threadIdx.x;      // 5760*256 == WELEM
    float f = w[i];
    short h = f2bf(f);
    wnh[i] = h;
    wnl[i] = f2bf(f - bf2f(h));
}

// ---------------- p1: s0 partials, mfma over (4n x 8k) ----------------
template<int NS>
__global__ __launch_bounds__(256, 4) void caps_p1(
    const float* __restrict__ x, const short* __restrict__ wnh, const short* __restrict__ wnl,
    float* __restrict__ P)
{
    constexpr int NT = NN1 / NS;
    constexpr int QPW = NT / 16;     // quads per wave
    static_assert(NT % 16 == 0, "balanced quads");
    __shared__ float red[2][2560];

    const int ns = blockIdx.x, bt = blockIdx.y;
    const int tid = threadIdx.x, lane = tid & 63, wv = tid >> 6;
    const int lo = lane & 15, g = lane >> 4;
    const int btile = bt * 16;

    f32x4 acc[10];
#pragma unroll
    for (int c = 0; c < 10; ++c) acc[c] = ZERO4;

#pragma unroll 2
    for (int it = 0; it < QPW; ++it) {
        const int n0 = ns * NT + (wv * QPW + it) * 4;
        const float* px = x + (size_t)(btile + lo) * XB + (size_t)(n0 + g) * 8;
        f32x4 x0 = *(const f32x4*)px;
        f32x4 x1 = *(const f32x4*)(px + 4);
        bf16x8 ah, al;
        cvt_hilo8(x0, x1, ah, al);
#pragma unroll
        for (int c = 0; c < 10; ++c) {
            size_t off = (((size_t)c * NN1 + n0 + g) * 16 + lo) * 8;
            bf16x8 bh = *(const bf16x8*)(wnh + off);
            bf16x8 bl = *(const bf16x8*)(wnl + off);
            acc[c] = MFMA32(ah, bh, acc[c]);
            acc[c] = MFMA32(al, bh, acc[c]);
            acc[c] = MFMA32(ah, bl, acc[c]);
        }
    }

    // 4-wave reduce; C layout: col=lo=d, row=g*4+e=b-local
    if (wv == 1 || wv == 3) {
        float* s = red[wv >> 1];
#pragma unroll
        for (int c = 0; c < 10; ++c)
#pragma unroll
            for (int e = 0; e < 4; ++e) s[c * 256 + (g * 4 + e) * 16 + lo] = acc[c][e];
    }
    __syncthreads();
    if (wv == 0) {
#pragma unroll
        for (int c = 0; c < 10; ++c)
#pragma unroll
            for (int e = 0; e < 4; ++e) acc[c][e] += red[0][c * 256 + (g * 4 + e) * 16 + lo];
    } else if (wv == 2) {
#pragma unroll
        for (int c = 0; c < 10; ++c)
#pragma unroll
            for (int e = 0; e < 4; ++e) {
                int idx = c * 256 + (g * 4 + e) * 16 + lo;
                red[1][idx] += acc[c][e];
            }
    }
    __syncthreads();
    if (wv == 0) {
        float* dst = P + (size_t)ns * BB * CD;
#pragma unroll
        for (int c = 0; c < 10; ++c)
#pragma unroll
            for (int e = 0; e < 4; ++e)
                dst[(size_t)(btile + g * 4 + e) * CD + c * 16 + lo] =
                    acc[c][e] + red[1][c * 256 + (g * 4 + e) * 16 + lo];
    }
}

// ------- reduce over ns + squash(alpha*S) -------
__global__ void reduce_squash(const float* __restrict__ P, float* __restrict__ out,
                              int nsplit, float asq)
{
    int t = blockIdx.x * 256 + threadIdx.x;      // 320*256 == 81920
    float s = 0.f;
    const float* p = P + t;
    for (int ns = 0; ns < nsplit; ++ns, p += (size_t)BB * CD) s += *p;
    float sq = s * s;
#pragma unroll
    for (int m = 1; m < 16; m <<= 1) sq += __shfl_xor(sq, m, 64);
    float qq = asq * sq;
    float sc = qq / (1.f + qq) / sqrtf(sq);
    out[t] = s * sc;
}

// ---------------- p2: y-GEMM -> in-lane logits/softmax -> recompute + scale ----------------
template<int NS>
__global__ __launch_bounds__(256, 2) void caps_p2(
    const float* __restrict__ x,
    const short* __restrict__ wnh, const short* __restrict__ wnl,
    const float* __restrict__ o0, float* __restrict__ P)
{
    constexpr int NT = NN1 / NS;
    constexpr int PPW = NT / 8;      // n-pairs per wave
    static_assert(NT % 8 == 0, "balanced pairs");
    __shared__ float red[2][2560];

    const int ns = blockIdx.x, bt = blockIdx.y;
    const int tid = threadIdx.x, lane = tid & 63, wv = tid >> 6;
    const int lo = lane & 15, g = lane >> 4;
    const int btile = bt * 16;
    const int b = btile + lo;
    const int ghalf = g & 1;

    const short* wsel  = ghalf ? wnl : wnh;   // A k-blk pattern [hi|lo|hi|junk]; B zeroes blk3
    const short* wsel2 = wsel + opaque_zero();   // laundered base for pass-2 reloads (no CSE)
    const float* po0   = o0 + (size_t)b * CD + g * 4;   // o0[b, c*16 + g*4 + e]

    f32x4 acc[10];
#pragma unroll
    for (int c = 0; c < 10; ++c) acc[c] = ZERO4;

    const bf16x8 z8 = {0, 0, 0, 0, 0, 0, 0, 0};

    for (int it = 0; it < PPW; ++it) {
        const int n0 = ns * NT + (wv * PPW + it) * 2;
        const float* px = x + (size_t)b * XB + (size_t)n0 * 8;
        f32x4 x0a = *(const f32x4*)px,       x0b = *(const f32x4*)(px + 4);
        f32x4 x1a = *(const f32x4*)(px + 8), x1b = *(const f32x4*)(px + 12);

        bf16x8 xh0, xl0, xh1, xl1;
        cvt_hilo8(x0a, x0b, xh0, xl0);
        cvt_hilo8(x1a, x1b, xh1, xl1);

        // s1 B-fragments: [x_hi | x_hi | x_lo | 0] along K
        bf16x8 Bx0, Bx1;
        if (g == 3)      { Bx0 = z8;  Bx1 = z8;  }
        else if (g == 2) { Bx0 = xl0; Bx1 = xl1; }
        else             { Bx0 = xh0; Bx1 = xh1; }

        // ---- pass 1: y = x_hat -> in-lane logit partial -> shfl d-reduce ----
        float L0[10], L1[10];
#pragma unroll
        for (int c = 0; c < 10; ++c) {
            const short* ap = wsel + (((size_t)c * NN1 + n0) * 16 + lo) * 8;
            bf16x8 A0 = *(const bf16x8*)ap;
            bf16x8 A1 = *(const bf16x8*)(ap + 128);
            f32x4 y0 = MFMA32(A0, Bx0, ZERO4);
            f32x4 y1 = MFMA32(A1, Bx1, ZERO4);
            f32x4 ov = *(const f32x4*)(po0 + c * 16);
            float lp0 = y0[0]*ov[0] + y0[1]*ov[1] + y0[2]*ov[2] + y0[3]*ov[3];
            float lp1 = y1[0]*ov[0] + y1[1]*ov[1] + y1[2]*ov[2] + y1[3]*ov[3];
            lp0 += __shfl_xor(lp0, 16, 64);
            lp0 += __shfl_xor(lp0, 32, 64);
            lp1 += __shfl_xor(lp1, 16, 64);
            lp1 += __shfl_xor(lp1, 32, 64);
            L0[c] = lp0;
            L1[c] = lp1;
        }

        // ---- softmax for both n's, fully in-lane; L becomes c1 ----
        float mx0 = L0[0], mx1 = L1[0];
#pragma unroll
        for (int c = 1; c < 10; ++c) { mx0 = fmaxf(mx0, L0[c]); mx1 = fmaxf(mx1, L1[c]); }
        float d0 = 0.f, d1 = 0.f;
#pragma unroll
        for (int c = 0; c < 10; ++c) {
            L0[c] = __expf(L0[c] - mx0); d0 += L0[c];
            L1[c] = __expf(L1[c] - mx1); d1 += L1[c];
        }
        float i0 = 1.f / d0, i1 = 1.f / d1;

        // ---- pass 2: recompute y from laundered loads, acc += c1 * y ----
#pragma unroll
        for (int c = 0; c < 10; ++c) {
            const short* ap = wsel2 + (((size_t)c * NN1 + n0) * 16 + lo) * 8;
            bf16x8 A0 = *(const bf16x8*)ap;
            bf16x8 A1 = *(const bf16x8*)(ap + 128);
            f32x4 y0 = MFMA32(A0, Bx0, ZERO4);
            f32x4 y1 = MFMA32(A1, Bx1, ZERO4);
            float c0f = L0[c] * i0, c1f = L1[c] * i1;
#pragma unroll
            for (int e = 0; e < 4; ++e) acc[c][e] += c0f * y0[e] + c1f * y1[e];
        }
    }

    // 4-wave reduce; C layout: col=lo=b-local, row=g*4+e=d
    if (wv == 1 || wv == 3) {
        float* s = red[wv >> 1];
#pragma unroll
        for (int c = 0; c < 10; ++c)
#pragma unroll
            for (int e = 0; e < 4; ++e) s[c * 256 + (g * 4 + e) * 16 + lo] = acc[c][e];
    }
    __syncthreads();
    if (wv == 0) {
#pragma unroll
        for (int c = 0; c < 10; ++c)
#pragma unroll
            for (int e = 0; e < 4; ++e) acc[c][e] += red[0][c * 256 + (g * 4 + e) * 16 + lo];
    } else if (wv == 2) {
#pragma unroll
        for (int c = 0; c < 10; ++c)
#pragma unroll
            for (int e = 0; e < 4; ++e) {
                int idx = c * 256 + (g * 4 + e) * 16 + lo;
                red[1][idx] += acc[c][e];
            }
    }
    __syncthreads();
    if (wv == 0) {
        float* dst = P + (size_t)ns * BB * CD;
#pragma unroll
        for (int c = 0; c < 10; ++c)
#pragma unroll
            for (int e = 0; e < 4; ++e)
                dst[(size_t)(btile + lo) * CD + c * 16 + g * 4 + e] =
                    acc[c][e] + red[1][c * 256 + (g * 4 + e) * 16 + lo];
    }
}

extern "C" void kernel_launch(void* const* d_in, const int* in_sizes, int n_in,
                              void* d_out, int out_size, void* d_ws, size_t ws_size,
                              hipStream_t stream)
{
    (void)in_sizes; (void)n_in; (void)out_size;
    const float* x = (const float*)d_in[0];
    const float* w = (const float*)d_in[1];
    float* out = (float*)d_out;

    char* base = (char*)d_ws;
    short* wnh = (short*)(base);
    short* wnl = (short*)(base + 2949120);
    float* o0  = (float*)(base + 5898240);
    float* P   = (float*)(base + 6225920);
    const size_t fixed = 6225920, slab = (size_t)BB * CD * sizeof(float);

    p0<<<WELEM / 256, 256, 0, stream>>>(w, wnh, wnl);

#define LAUNCH_NS(NS1, NS2)                                                            \
    do {                                                                               \
        caps_p1<NS1><<<dim3(NS1, 32), 256, 0, stream>>>(x, wnh, wnl, P);               \
        reduce_squash<<<320, 256, 0, stream>>>(P, o0, NS1, 0.01f);                     \
        caps_p2<NS2><<<dim3(NS2, 32), 256, 0, stream>>>(x, wnh, wnl, o0, P);           \
        reduce_squash<<<320, 256, 0, stream>>>(P, out, NS2, 1.0f);                     \
    } while (0)

    if      (ws_size >= fixed + slab * 48) LAUNCH_NS(36, 48);   // p1: 2 quads/wave; p2: 3 pairs/wave
    else if (ws_size >= fixed + slab * 12) LAUNCH_NS(12, 12);
    else                                   LAUNCH_NS(4, 4);
#undef LAUNCH_NS
}